// Round 3
// baseline (524.403 us; speedup 1.0000x reference)
//
#include <hip/hip_runtime.h>
#include <hip/hip_bf16.h>
#include <stdint.h>

// Problem dims (fixed by setup_inputs)
#define T_DIM 2048
#define I_DIM 4096
#define O_DIM 4096
#define R_DIM 16
#define QBLK  32

typedef __bf16 bf16x8 __attribute__((ext_vector_type(8)));
typedef float  floatx4 __attribute__((ext_vector_type(4)));
typedef unsigned short ushort_t;

__device__ __forceinline__ ushort_t f2bf(float f) {
  unsigned u = __float_as_uint(f);
  u += 0x7FFFu + ((u >> 16) & 1u);   // round-to-nearest-even
  return (ushort_t)(u >> 16);
}

__device__ __forceinline__ float dot4(float4 a, float4 b) {
  return a.x * b.x + a.y * b.y + a.z * b.z + a.w * b.w;
}

// ---------------- prep_x: f32 -> bf16 (8 elems/thread) ----------------
__global__ __launch_bounds__(256) void k_prep_x(const float* __restrict__ x,
                                                ushort_t* __restrict__ xb) {
  int idx = blockIdx.x * 256 + threadIdx.x;   // 8-element chunk id
  const float4* xp = (const float4*)x;
  float4 a = xp[idx * 2], b = xp[idx * 2 + 1];
  union { ushort_t u[8]; uint4 v; } r;
  r.u[0] = f2bf(a.x); r.u[1] = f2bf(a.y); r.u[2] = f2bf(a.z); r.u[3] = f2bf(a.w);
  r.u[4] = f2bf(b.x); r.u[5] = f2bf(b.y); r.u[6] = f2bf(b.z); r.u[7] = f2bf(b.w);
  ((uint4*)xb)[idx] = r.v;
}

// ---------------- prep_w: dequant int32 codes -> bf16 W ----------------
__global__ __launch_bounds__(256) void k_prep_w(const int* __restrict__ q,
                                                const float* __restrict__ scales,
                                                ushort_t* __restrict__ wb) {
  int idx = blockIdx.x * 256 + threadIdx.x;   // 8-element chunk id
  int o  = idx >> 9;                          // I/8 = 512 chunks per row
  int i0 = (idx & 511) * 8;                   // 8-aligned -> same quant block
  float s = scales[o * (I_DIM / QBLK) + (i0 >> 5)];
  const int4* qp = (const int4*)(q + (size_t)o * I_DIM + i0);
  int4 q0 = qp[0], q1 = qp[1];
  union { ushort_t u[8]; uint4 v; } r;
  r.u[0] = f2bf((float)(q0.x - 8) * s); r.u[1] = f2bf((float)(q0.y - 8) * s);
  r.u[2] = f2bf((float)(q0.z - 8) * s); r.u[3] = f2bf((float)(q0.w - 8) * s);
  r.u[4] = f2bf((float)(q1.x - 8) * s); r.u[5] = f2bf((float)(q1.y - 8) * s);
  r.u[6] = f2bf((float)(q1.z - 8) * s); r.u[7] = f2bf((float)(q1.w - 8) * s);
  ((uint4*)wb)[idx] = r.v;
}

// ---------------- xd = alpha * (x @ down^T)  [T,16] f32 ----------------
__global__ __launch_bounds__(256) void k_xd(const float* __restrict__ x,
                                            const float* __restrict__ down,
                                            const float* __restrict__ alphap,
                                            float* __restrict__ xd) {
  __shared__ float ds[16 * 512];              // 32 KB: down[0:16][ib:ib+512)
  const int tid = threadIdx.x;
  const int tl = tid >> 5, s = tid & 31;
  const int t = blockIdx.x * 8 + tl;
  float acc[16];
#pragma unroll
  for (int r = 0; r < 16; ++r) acc[r] = 0.f;

  for (int c = 0; c < 8; ++c) {
    const int ib = c * 512;
    __syncthreads();
#pragma unroll
    for (int j = 0; j < 8; ++j) {
      int e = j * 256 + tid;                  // float4 slot, 2048 total
      int r = e >> 7, col = e & 127;
      ((float4*)ds)[e] = ((const float4*)(down + (size_t)r * I_DIM + ib))[col];
    }
    __syncthreads();
#pragma unroll
    for (int j = 0; j < 4; ++j) {
      float4 xv = ((const float4*)(x + (size_t)t * I_DIM + ib))[s + 32 * j];
#pragma unroll
      for (int r = 0; r < 16; ++r) {
        float4 dv = ((const float4*)ds)[r * 128 + s + 32 * j];
        acc[r] += dot4(xv, dv);
      }
    }
  }
  const float al = alphap[0];
#pragma unroll
  for (int r = 0; r < 16; ++r) {
    float v = acc[r];
    v += __shfl_down(v, 16, 32);
    v += __shfl_down(v, 8, 32);
    v += __shfl_down(v, 4, 32);
    v += __shfl_down(v, 2, 32);
    v += __shfl_down(v, 1, 32);
    if (s == 0) xd[t * 16 + r] = v * al;
  }
}

// ---------------- main GEMM: y = xb @ wb^T + lora-epilogue + bias ------
// m97-exact structure: 128x128 tile, BK=64, 4 waves (2x2), 4x4
// mfma_16x16x32_bf16/wave, global_load_lds width=16 with LINEAR source
// order (lane -> ascending address; the R1/R2 XOR-swizzled source
// defeated the LDS-DMA coalescer -> 358us latency-bound disaster).
// LDS layout == global layout (row-major 128x64). Bank conflicts on the
// fragment ds_reads are accepted (m97/m98 precedent: ~2x on ds_read,
// small slice of budget).
__global__ __launch_bounds__(256) void k_gemm(const ushort_t* __restrict__ xb,
                                              const ushort_t* __restrict__ wb,
                                              const float* __restrict__ bias,
                                              const float* __restrict__ xd,
                                              const float* __restrict__ up,
                                              float* __restrict__ y) {
  __shared__ __align__(16) ushort_t As[128 * 64];   // 16 KB
  __shared__ __align__(16) ushort_t Bs[128 * 64];   // 16 KB
  const int tid = threadIdx.x;
  const int oT = blockIdx.x * 128, tT = blockIdx.y * 128;
  const int lane = tid & 63;
  const int wv = __builtin_amdgcn_readfirstlane(tid >> 6);  // wave id, scalar
  const int wm = wv >> 1, wn = wv & 1;
  const int quad = lane >> 4, m16 = lane & 15;

  floatx4 acc[4][4] = {};

  for (int kt = 0; kt < I_DIM / 64; ++kt) {
    const int k0 = kt * 64;
    // Staging: 1024 16B-segments per tile; seg = linear; row=seg>>3,
    // col-seg=seg&7. Lane addresses ascend within each 8-lane row run.
#pragma unroll
    for (int it = 0; it < 4; ++it) {
      const int seg_base = (it * 4 + wv) * 64;          // wave-uniform
      const int seg = seg_base + lane;
      const int r = seg >> 3;
      const int cg = seg & 7;
      __builtin_amdgcn_global_load_lds(
          (const __attribute__((address_space(1))) char*)(xb + (size_t)(tT + r) * I_DIM + k0 + cg * 8),
          (__attribute__((address_space(3))) char*)(As + seg_base * 8), 16, 0, 0);
      __builtin_amdgcn_global_load_lds(
          (const __attribute__((address_space(1))) char*)(wb + (size_t)(oT + r) * I_DIM + k0 + cg * 8),
          (__attribute__((address_space(3))) char*)(Bs + seg_base * 8), 16, 0, 0);
    }
    __syncthreads();   // compiler emits s_waitcnt vmcnt(0) before s_barrier

#pragma unroll
    for (int ks2 = 0; ks2 < 2; ++ks2) {       // two K=32 steps per BK=64
      const int c = ks2 * 4 + quad;           // k-segment (8 bf16) index
      bf16x8 af[4], bfr[4];
#pragma unroll
      for (int im = 0; im < 4; ++im) {
        int m = wm * 64 + im * 16 + m16;
        af[im] = *(const bf16x8*)(As + (m * 8 + c) * 8);
      }
#pragma unroll
      for (int in_ = 0; in_ < 4; ++in_) {
        int n = wn * 64 + in_ * 16 + m16;
        bfr[in_] = *(const bf16x8*)(Bs + (n * 8 + c) * 8);
      }
#pragma unroll
      for (int im = 0; im < 4; ++im)
#pragma unroll
        for (int in_ = 0; in_ < 4; ++in_)
          acc[im][in_] = __builtin_amdgcn_mfma_f32_16x16x32_bf16(
              af[im], bfr[in_], acc[im][in_], 0, 0, 0);
    }
    __syncthreads();
  }

  // Epilogue: y[t][o] = acc + dot16(xd[t], up[o]) + bias[o]
  // C/D layout: row = quad*4+reg, col = lane&15 (m89-verified).
#pragma unroll
  for (int im = 0; im < 4; ++im) {
#pragma unroll
    for (int reg = 0; reg < 4; ++reg) {
      int t = tT + wm * 64 + im * 16 + quad * 4 + reg;
      const float4* xr = (const float4*)(xd + t * 16);
      float4 x0 = xr[0], x1 = xr[1], x2 = xr[2], x3 = xr[3];
#pragma unroll
      for (int in_ = 0; in_ < 4; ++in_) {
        int o = oT + wn * 64 + in_ * 16 + m16;
        const float4* ur = (const float4*)(up + (size_t)o * R_DIM);
        float lv = dot4(x0, ur[0]) + dot4(x1, ur[1]) +
                   dot4(x2, ur[2]) + dot4(x3, ur[3]);
        y[(size_t)t * O_DIM + o] = acc[im][in_][reg] + lv + bias[o];
      }
    }
  }
}

extern "C" void kernel_launch(void* const* d_in, const int* in_sizes, int n_in,
                              void* d_out, int out_size, void* d_ws, size_t ws_size,
                              hipStream_t stream) {
  const float* x      = (const float*)d_in[0];
  const int*   q      = (const int*)d_in[1];
  const float* scales = (const float*)d_in[2];
  const float* up     = (const float*)d_in[3];
  const float* down   = (const float*)d_in[4];
  const float* alpha  = (const float*)d_in[5];
  const float* bias   = (const float*)d_in[6];
  float* y = (float*)d_out;

  // ws layout: xb bf16 [T,I] (16 MB) | wb bf16 [O,I] (32 MB) | xd f32 [T,16]
  ushort_t* xb = (ushort_t*)d_ws;
  ushort_t* wb = (ushort_t*)((char*)d_ws + (size_t)T_DIM * I_DIM * 2);
  float*    xd = (float*)((char*)d_ws + (size_t)T_DIM * I_DIM * 2 + (size_t)O_DIM * I_DIM * 2);

  hipLaunchKernelGGL(k_prep_x, dim3((T_DIM * I_DIM) / 8 / 256), dim3(256), 0, stream, x, xb);
  hipLaunchKernelGGL(k_prep_w, dim3((O_DIM * I_DIM) / 8 / 256), dim3(256), 0, stream, q, scales, wb);
  hipLaunchKernelGGL(k_xd, dim3(T_DIM / 8), dim3(256), 0, stream, x, down, alpha, xd);
  hipLaunchKernelGGL(k_gemm, dim3(O_DIM / 128, T_DIM / 128), dim3(256), 0, stream,
                     xb, wb, bias, xd, up, y);
}

// Round 4
// 489.972 us; speedup vs baseline: 1.0703x; 1.0703x over previous
//
#include <hip/hip_runtime.h>
#include <hip/hip_bf16.h>
#include <stdint.h>

// Problem dims (fixed by setup_inputs)
#define T_DIM 2048
#define I_DIM 4096
#define O_DIM 4096
#define R_DIM 16
#define QBLK  32

typedef __bf16 bf16x8 __attribute__((ext_vector_type(8)));
typedef float  floatx4 __attribute__((ext_vector_type(4)));
typedef unsigned short ushort_t;

#define AS1 __attribute__((address_space(1)))
#define AS3 __attribute__((address_space(3)))

__device__ __forceinline__ ushort_t f2bf(float f) {
  unsigned u = __float_as_uint(f);
  u += 0x7FFFu + ((u >> 16) & 1u);   // round-to-nearest-even
  return (ushort_t)(u >> 16);
}

__device__ __forceinline__ float dot4(float4 a, float4 b) {
  return a.x * b.x + a.y * b.y + a.z * b.z + a.w * b.w;
}

// ---------------- prep_x: f32 -> bf16 (8 elems/thread) ----------------
__global__ __launch_bounds__(256) void k_prep_x(const float* __restrict__ x,
                                                ushort_t* __restrict__ xb) {
  int idx = blockIdx.x * 256 + threadIdx.x;   // 8-element chunk id
  const float4* xp = (const float4*)x;
  float4 a = xp[idx * 2], b = xp[idx * 2 + 1];
  union { ushort_t u[8]; uint4 v; } r;
  r.u[0] = f2bf(a.x); r.u[1] = f2bf(a.y); r.u[2] = f2bf(a.z); r.u[3] = f2bf(a.w);
  r.u[4] = f2bf(b.x); r.u[5] = f2bf(b.y); r.u[6] = f2bf(b.z); r.u[7] = f2bf(b.w);
  ((uint4*)xb)[idx] = r.v;
}

// ---------------- prep_w: dequant int32 codes -> bf16 W ----------------
__global__ __launch_bounds__(256) void k_prep_w(const int* __restrict__ q,
                                                const float* __restrict__ scales,
                                                ushort_t* __restrict__ wb) {
  int idx = blockIdx.x * 256 + threadIdx.x;   // 8-element chunk id
  int o  = idx >> 9;                          // I/8 = 512 chunks per row
  int i0 = (idx & 511) * 8;                   // 8-aligned -> same quant block
  float s = scales[o * (I_DIM / QBLK) + (i0 >> 5)];
  const int4* qp = (const int4*)(q + (size_t)o * I_DIM + i0);
  int4 q0 = qp[0], q1 = qp[1];
  union { ushort_t u[8]; uint4 v; } r;
  r.u[0] = f2bf((float)(q0.x - 8) * s); r.u[1] = f2bf((float)(q0.y - 8) * s);
  r.u[2] = f2bf((float)(q0.z - 8) * s); r.u[3] = f2bf((float)(q0.w - 8) * s);
  r.u[4] = f2bf((float)(q1.x - 8) * s); r.u[5] = f2bf((float)(q1.y - 8) * s);
  r.u[6] = f2bf((float)(q1.z - 8) * s); r.u[7] = f2bf((float)(q1.w - 8) * s);
  ((uint4*)wb)[idx] = r.v;
}

// ---------------- xd = alpha * (x @ down^T)  [T,16] f32 ----------------
__global__ __launch_bounds__(256) void k_xd(const float* __restrict__ x,
                                            const float* __restrict__ down,
                                            const float* __restrict__ alphap,
                                            float* __restrict__ xd) {
  __shared__ float ds[16 * 512];              // 32 KB: down[0:16][ib:ib+512)
  const int tid = threadIdx.x;
  const int tl = tid >> 5, s = tid & 31;
  const int t = blockIdx.x * 8 + tl;
  float acc[16];
#pragma unroll
  for (int r = 0; r < 16; ++r) acc[r] = 0.f;

  for (int c = 0; c < 8; ++c) {
    const int ib = c * 512;
    __syncthreads();
#pragma unroll
    for (int j = 0; j < 8; ++j) {
      int e = j * 256 + tid;                  // float4 slot, 2048 total
      int r = e >> 7, col = e & 127;
      ((float4*)ds)[e] = ((const float4*)(down + (size_t)r * I_DIM + ib))[col];
    }
    __syncthreads();
#pragma unroll
    for (int j = 0; j < 4; ++j) {
      float4 xv = ((const float4*)(x + (size_t)t * I_DIM + ib))[s + 32 * j];
#pragma unroll
      for (int r = 0; r < 16; ++r) {
        float4 dv = ((const float4*)ds)[r * 128 + s + 32 * j];
        acc[r] += dot4(xv, dv);
      }
    }
  }
  const float al = alphap[0];
#pragma unroll
  for (int r = 0; r < 16; ++r) {
    float v = acc[r];
    v += __shfl_down(v, 16, 32);
    v += __shfl_down(v, 8, 32);
    v += __shfl_down(v, 4, 32);
    v += __shfl_down(v, 2, 32);
    v += __shfl_down(v, 1, 32);
    if (s == 0) xd[t * 16 + r] = v * al;
  }
}

// ---------------- main GEMM: y = xb @ wb^T + lora-epilogue + bias ------
// 128x128 tile, BK=64, 4 waves (2x2), 4x4 mfma_16x16x32_bf16 per wave.
// R4 structural change: DOUBLE-BUFFERED pipeline for the 2-blocks/CU
// latency-bound regime (R1-R3 all ~14K cyc/iter with every pipe idle):
//   per iter: vmcnt(0) [only cur-buffer loads outstanding] -> s_barrier
//   -> 16 fragment ds_reads (R2 conflict-free XOR swizzle)
//   -> issue 8 prefetch loads for kt+1 into other buffer
//   -> 32 MFMAs (prefetch in flight through MFMA + next stage)
// One raw s_barrier per iter (not 2 full __syncthreads drains).
__global__ __launch_bounds__(256) void k_gemm(const ushort_t* __restrict__ xb,
                                              const ushort_t* __restrict__ wb,
                                              const float* __restrict__ bias,
                                              const float* __restrict__ xd,
                                              const float* __restrict__ up,
                                              float* __restrict__ y) {
  // [buf][mat][row*64 + swizzled-k]  : 2 * 2 * 128*64 ushort = 64 KB
  __shared__ __align__(16) ushort_t sm[2 * 2 * 128 * 64];
  const int tid = threadIdx.x;
  const int oT = blockIdx.x * 128, tT = blockIdx.y * 128;
  const int lane = tid & 63;
  const int wv = tid >> 6;
  const int wm = wv >> 1, wn = wv & 1;
  const int quad = lane >> 4, m16 = lane & 15;

  floatx4 acc[4][4] = {};

  // Stage both 128x64 tiles for k-offset k0 into buffer `buf`.
  // seg = linear 16B-segment id; row=seg>>3; global col-seg=(seg&7)^(row&7)
  // (XOR swizzle -> fragment reads conflict-free; measured 0 in R2).
  auto stage = [&](int buf, int k0) {
#pragma unroll
    for (int it = 0; it < 4; ++it) {
      const int seg_base = (it * 4 + wv) * 64;          // wave-uniform
      const int seg = seg_base + lane;
      const int r = seg >> 3;
      const int cg = (seg & 7) ^ (r & 7);
      __builtin_amdgcn_global_load_lds(
          (const AS1 char*)(xb + (size_t)(tT + r) * I_DIM + k0 + cg * 8),
          (AS3 char*)(sm + buf * 16384 + seg_base * 8), 16, 0, 0);
      __builtin_amdgcn_global_load_lds(
          (const AS1 char*)(wb + (size_t)(oT + r) * I_DIM + k0 + cg * 8),
          (AS3 char*)(sm + buf * 16384 + 8192 + seg_base * 8), 16, 0, 0);
    }
  };

  // One pipelined K-step: compute on `buf` (already staged), prefetch k0n
  // into buf^1. At entry, the only outstanding vm ops are buf's 8 loads.
  auto body = [&](int buf, int k0n) {
    asm volatile("s_waitcnt vmcnt(0)" ::: "memory");  // own cur-buf loads landed
    asm volatile("s_barrier" ::: "memory");           // all waves' cur-buf landed
    const ushort_t* A = sm + buf * 16384;
    const ushort_t* B = sm + buf * 16384 + 8192;
    bf16x8 af[2][4], bfr[2][4];
#pragma unroll
    for (int ks2 = 0; ks2 < 2; ++ks2) {
      const int c = ks2 * 4 + quad;
#pragma unroll
      for (int i = 0; i < 4; ++i) {
        int m = wm * 64 + i * 16 + m16;
        af[ks2][i] = *(const bf16x8*)(A + (m * 8 + (c ^ (m & 7))) * 8);
        int n = wn * 64 + i * 16 + m16;
        bfr[ks2][i] = *(const bf16x8*)(B + (n * 8 + (c ^ (n & 7))) * 8);
      }
    }
    stage(buf ^ 1, k0n);                // prefetch flies during MFMAs
#pragma unroll
    for (int ks2 = 0; ks2 < 2; ++ks2)
#pragma unroll
      for (int im = 0; im < 4; ++im)
#pragma unroll
        for (int in_ = 0; in_ < 4; ++in_)
          acc[im][in_] = __builtin_amdgcn_mfma_f32_16x16x32_bf16(
              af[ks2][im], bfr[ks2][in_], acc[im][in_], 0, 0, 0);
  };

  stage(0, 0);
  for (int kt = 0; kt < I_DIM / 64; kt += 2) {
    body(0, ((kt + 1) & 63) * 64);      // last iter wrap-prefetches k0=0:
    body(1, ((kt + 2) & 63) * 64);      // harmless, keeps count uniform
  }

  // Epilogue: y[t][o] = acc + dot16(xd[t], up[o]) + bias[o]
  // C/D layout: row = quad*4+reg, col = lane&15 (m89-verified).
#pragma unroll
  for (int im = 0; im < 4; ++im) {
#pragma unroll
    for (int reg = 0; reg < 4; ++reg) {
      int t = tT + wm * 64 + im * 16 + quad * 4 + reg;
      const float4* xr = (const float4*)(xd + t * 16);
      float4 x0 = xr[0], x1 = xr[1], x2 = xr[2], x3 = xr[3];
#pragma unroll
      for (int in_ = 0; in_ < 4; ++in_) {
        int o = oT + wn * 64 + in_ * 16 + m16;
        const float4* ur = (const float4*)(up + (size_t)o * R_DIM);
        float lv = dot4(x0, ur[0]) + dot4(x1, ur[1]) +
                   dot4(x2, ur[2]) + dot4(x3, ur[3]);
        y[(size_t)t * O_DIM + o] = acc[im][in_][reg] + lv + bias[o];
      }
    }
  }
}

extern "C" void kernel_launch(void* const* d_in, const int* in_sizes, int n_in,
                              void* d_out, int out_size, void* d_ws, size_t ws_size,
                              hipStream_t stream) {
  const float* x      = (const float*)d_in[0];
  const int*   q      = (const int*)d_in[1];
  const float* scales = (const float*)d_in[2];
  const float* up     = (const float*)d_in[3];
  const float* down   = (const float*)d_in[4];
  const float* alpha  = (const float*)d_in[5];
  const float* bias   = (const float*)d_in[6];
  float* y = (float*)d_out;

  // ws layout: xb bf16 [T,I] (16 MB) | wb bf16 [O,I] (32 MB) | xd f32 [T,16]
  ushort_t* xb = (ushort_t*)d_ws;
  ushort_t* wb = (ushort_t*)((char*)d_ws + (size_t)T_DIM * I_DIM * 2);
  float*    xd = (float*)((char*)d_ws + (size_t)T_DIM * I_DIM * 2 + (size_t)O_DIM * I_DIM * 2);

  hipLaunchKernelGGL(k_prep_x, dim3((T_DIM * I_DIM) / 8 / 256), dim3(256), 0, stream, x, xb);
  hipLaunchKernelGGL(k_prep_w, dim3((O_DIM * I_DIM) / 8 / 256), dim3(256), 0, stream, q, scales, wb);
  hipLaunchKernelGGL(k_xd, dim3(T_DIM / 8), dim3(256), 0, stream, x, down, alpha, xd);
  hipLaunchKernelGGL(k_gemm, dim3(O_DIM / 128, T_DIM / 128), dim3(256), 0, stream,
                     xb, wb, bias, xd, up, y);
}

// Round 5
// 465.701 us; speedup vs baseline: 1.1260x; 1.0521x over previous
//
#include <hip/hip_runtime.h>
#include <hip/hip_bf16.h>
#include <stdint.h>

// Problem dims (fixed by setup_inputs)
#define T_DIM 2048
#define I_DIM 4096
#define O_DIM 4096
#define R_DIM 16
#define QBLK  32

typedef __bf16 bf16x8 __attribute__((ext_vector_type(8)));
typedef float  floatx4 __attribute__((ext_vector_type(4)));
typedef unsigned short ushort_t;

#define AS1 __attribute__((address_space(1)))
#define AS3 __attribute__((address_space(3)))

__device__ __forceinline__ ushort_t f2bf(float f) {
  unsigned u = __float_as_uint(f);
  u += 0x7FFFu + ((u >> 16) & 1u);   // round-to-nearest-even
  return (ushort_t)(u >> 16);
}

__device__ __forceinline__ float dot4(float4 a, float4 b) {
  return a.x * b.x + a.y * b.y + a.z * b.z + a.w * b.w;
}

// ------------- merged prep: xb=bf16(x) | wb=dequant(q) | xd=alpha*x@down^T
// Block ranges: [0,4096) prep_x, [4096,12288) prep_w, [12288,12544) xd.
__global__ __launch_bounds__(256) void k_prep(const float* __restrict__ x,
                                              const int* __restrict__ q,
                                              const float* __restrict__ scales,
                                              const float* __restrict__ down,
                                              const float* __restrict__ alphap,
                                              ushort_t* __restrict__ xb,
                                              ushort_t* __restrict__ wb,
                                              float* __restrict__ xd) {
  __shared__ float ds[16 * 512];              // 32 KB, used by xd branch only
  const int b = blockIdx.x, tid = threadIdx.x;

  if (b < 4096) {                             // ---- prep_x
    int idx = b * 256 + tid;                  // 8-element chunk id
    const float4* xp = (const float4*)x;
    float4 a = xp[idx * 2], c = xp[idx * 2 + 1];
    union { ushort_t u[8]; uint4 v; } r;
    r.u[0] = f2bf(a.x); r.u[1] = f2bf(a.y); r.u[2] = f2bf(a.z); r.u[3] = f2bf(a.w);
    r.u[4] = f2bf(c.x); r.u[5] = f2bf(c.y); r.u[6] = f2bf(c.z); r.u[7] = f2bf(c.w);
    ((uint4*)xb)[idx] = r.v;
    return;
  }
  if (b < 12288) {                            // ---- prep_w
    int idx = (b - 4096) * 256 + tid;
    int o  = idx >> 9;
    int i0 = (idx & 511) * 8;
    float s = scales[o * (I_DIM / QBLK) + (i0 >> 5)];
    const int4* qp = (const int4*)(q + (size_t)o * I_DIM + i0);
    int4 q0 = qp[0], q1 = qp[1];
    union { ushort_t u[8]; uint4 v; } r;
    r.u[0] = f2bf((float)(q0.x - 8) * s); r.u[1] = f2bf((float)(q0.y - 8) * s);
    r.u[2] = f2bf((float)(q0.z - 8) * s); r.u[3] = f2bf((float)(q0.w - 8) * s);
    r.u[4] = f2bf((float)(q1.x - 8) * s); r.u[5] = f2bf((float)(q1.y - 8) * s);
    r.u[6] = f2bf((float)(q1.z - 8) * s); r.u[7] = f2bf((float)(q1.w - 8) * s);
    ((uint4*)wb)[idx] = r.v;
    return;
  }
  // ---- xd = alpha * (x @ down^T), 8 tokens per block
  {
    const int blk = b - 12288;
    const int tl = tid >> 5, s = tid & 31;
    const int t = blk * 8 + tl;
    float acc[16];
#pragma unroll
    for (int r = 0; r < 16; ++r) acc[r] = 0.f;
    for (int c = 0; c < 8; ++c) {
      const int ib = c * 512;
      __syncthreads();
#pragma unroll
      for (int j = 0; j < 8; ++j) {
        int e = j * 256 + tid;
        int r = e >> 7, col = e & 127;
        ((float4*)ds)[e] = ((const float4*)(down + (size_t)r * I_DIM + ib))[col];
      }
      __syncthreads();
#pragma unroll
      for (int j = 0; j < 4; ++j) {
        float4 xv = ((const float4*)(x + (size_t)t * I_DIM + ib))[s + 32 * j];
#pragma unroll
        for (int r = 0; r < 16; ++r) {
          float4 dv = ((const float4*)ds)[r * 128 + s + 32 * j];
          acc[r] += dot4(xv, dv);
        }
      }
    }
    const float al = alphap[0];
#pragma unroll
    for (int r = 0; r < 16; ++r) {
      float v = acc[r];
      v += __shfl_down(v, 16, 32);
      v += __shfl_down(v, 8, 32);
      v += __shfl_down(v, 4, 32);
      v += __shfl_down(v, 2, 32);
      v += __shfl_down(v, 1, 32);
      if (s == 0) xd[t * 16 + r] = v * al;
    }
  }
}

// ---------------- main GEMM: y = xb @ wb^T + lora-epilogue + bias ------
// R5 macro change: 128(T) x 64(O) tile -> grid 64x16 = 1024 blocks =
// 4 blocks/CU (R1-R4's 512-block grid was 2/CU; m102's shape curve shows
// this latency-bound structure is residency-dominated: 320 TF @1blk/CU
// vs 833 TF @4blk/CU). Single-buffered m97-exact two-barrier K-loop
// (R4's dbuf was only -10% and halves LDS residency). Wave tile 64x32,
// acc 4x2 (32 VGPRs) to keep VGPR <=~128 -> 4 waves/SIMD headroom.
__global__ __launch_bounds__(256) void k_gemm(const ushort_t* __restrict__ xb,
                                              const ushort_t* __restrict__ wb,
                                              const float* __restrict__ bias,
                                              const float* __restrict__ xd,
                                              const float* __restrict__ up,
                                              float* __restrict__ y) {
  __shared__ __align__(16) ushort_t As[128 * 64];   // 16 KB
  __shared__ __align__(16) ushort_t Bs[64 * 64];    // 8 KB
  const int tid = threadIdx.x;
  const int oT = blockIdx.x * 64, tT = blockIdx.y * 128;
  const int lane = tid & 63;
  const int wv = tid >> 6;
  const int wm = wv >> 1, wn = wv & 1;        // 2x2 waves: T-half, O-half
  const int quad = lane >> 4, m16 = lane & 15;

  floatx4 acc[4][2] = {};

  for (int kt = 0; kt < I_DIM / 64; ++kt) {
    const int k0 = kt * 64;
    // A tile: 128x64 = 1024 16B-segs, 4 instr/wave. XOR swizzle on col-seg.
#pragma unroll
    for (int it = 0; it < 4; ++it) {
      const int seg_base = wv * 256 + it * 64;        // wave-uniform
      const int seg = seg_base + lane;
      const int r = seg >> 3;
      const int cg = (seg & 7) ^ (r & 7);
      __builtin_amdgcn_global_load_lds(
          (const AS1 char*)(xb + (size_t)(tT + r) * I_DIM + k0 + cg * 8),
          (AS3 char*)(As + seg_base * 8), 16, 0, 0);
    }
    // B tile: 64x64 = 512 segs, 2 instr/wave.
#pragma unroll
    for (int it = 0; it < 2; ++it) {
      const int seg_base = wv * 128 + it * 64;
      const int seg = seg_base + lane;
      const int r = seg >> 3;
      const int cg = (seg & 7) ^ (r & 7);
      __builtin_amdgcn_global_load_lds(
          (const AS1 char*)(wb + (size_t)(oT + r) * I_DIM + k0 + cg * 8),
          (AS3 char*)(Bs + seg_base * 8), 16, 0, 0);
    }
    __syncthreads();   // compiler emits s_waitcnt vmcnt(0) before s_barrier

#pragma unroll
    for (int ks2 = 0; ks2 < 2; ++ks2) {       // two K=32 steps per BK=64
      const int c = ks2 * 4 + quad;
      bf16x8 af[4], bfr[2];
#pragma unroll
      for (int im = 0; im < 4; ++im) {
        int m = wm * 64 + im * 16 + m16;
        af[im] = *(const bf16x8*)(As + (m * 8 + (c ^ (m & 7))) * 8);
      }
#pragma unroll
      for (int in_ = 0; in_ < 2; ++in_) {
        int n = wn * 32 + in_ * 16 + m16;
        bfr[in_] = *(const bf16x8*)(Bs + (n * 8 + (c ^ (n & 7))) * 8);
      }
#pragma unroll
      for (int im = 0; im < 4; ++im)
#pragma unroll
        for (int in_ = 0; in_ < 2; ++in_)
          acc[im][in_] = __builtin_amdgcn_mfma_f32_16x16x32_bf16(
              af[im], bfr[in_], acc[im][in_], 0, 0, 0);
    }
    __syncthreads();
  }

  // Epilogue: y[t][o] = acc + dot16(xd[t], up[o]) + bias[o]
  // C/D layout: row = quad*4+reg, col = lane&15 (m89-verified).
#pragma unroll
  for (int im = 0; im < 4; ++im) {
#pragma unroll
    for (int reg = 0; reg < 4; ++reg) {
      int t = tT + wm * 64 + im * 16 + quad * 4 + reg;
      const float4* xr = (const float4*)(xd + t * 16);
      float4 x0 = xr[0], x1 = xr[1], x2 = xr[2], x3 = xr[3];
#pragma unroll
      for (int in_ = 0; in_ < 2; ++in_) {
        int o = oT + wn * 32 + in_ * 16 + m16;
        const float4* ur = (const float4*)(up + (size_t)o * R_DIM);
        float lv = dot4(x0, ur[0]) + dot4(x1, ur[1]) +
                   dot4(x2, ur[2]) + dot4(x3, ur[3]);
        y[(size_t)t * O_DIM + o] = acc[im][in_][reg] + lv + bias[o];
      }
    }
  }
}

extern "C" void kernel_launch(void* const* d_in, const int* in_sizes, int n_in,
                              void* d_out, int out_size, void* d_ws, size_t ws_size,
                              hipStream_t stream) {
  const float* x      = (const float*)d_in[0];
  const int*   q      = (const int*)d_in[1];
  const float* scales = (const float*)d_in[2];
  const float* up     = (const float*)d_in[3];
  const float* down   = (const float*)d_in[4];
  const float* alpha  = (const float*)d_in[5];
  const float* bias   = (const float*)d_in[6];
  float* y = (float*)d_out;

  // ws layout: xb bf16 [T,I] (16 MB) | wb bf16 [O,I] (32 MB) | xd f32 [T,16]
  ushort_t* xb = (ushort_t*)d_ws;
  ushort_t* wb = (ushort_t*)((char*)d_ws + (size_t)T_DIM * I_DIM * 2);
  float*    xd = (float*)((char*)d_ws + (size_t)T_DIM * I_DIM * 2 + (size_t)O_DIM * I_DIM * 2);

  hipLaunchKernelGGL(k_prep, dim3(4096 + 8192 + 256), dim3(256), 0, stream,
                     x, q, scales, down, alpha, xb, wb, xd);
  hipLaunchKernelGGL(k_gemm, dim3(O_DIM / 64, T_DIM / 128), dim3(256), 0, stream,
                     xb, wb, bias, xd, up, y);
}